// Round 7
// baseline (242.028 us; speedup 1.0000x reference)
//
#include <hip/hip_runtime.h>
#include <hip/hip_bf16.h>
#include <math.h>

// MHSA, fp32 I/O, bf16 MFMA internally.
// R7 = R6 with the V-epilogue store-address bug fixed (was racing on p0+16i).
// k_qkv: sorted weight columns (Q|K|V each (h,v)-ordered), BK=64, XOR-swizzled
// LDS, in-kernel fp32->bf16 A staging, V epilogue transposed through LDS for
// 16B stores. attn/merge unchanged from R5.

#define B_  8
#define P_  1024
#define T_  768
#define H_  12
#define DV  64
#define F3  2304   // 3*H*DV
#define HD  768    // H*DV
#define BK  32

typedef float  f32x4  __attribute__((ext_vector_type(4)));
typedef __bf16 bf16x4 __attribute__((ext_vector_type(4)));
typedef __bf16 bf16x8 __attribute__((ext_vector_type(8)));

__device__ __forceinline__ void gload16(const void* g, void* l) {
    __builtin_amdgcn_global_load_lds((const __attribute__((address_space(1))) void*)g,
                                     (__attribute__((address_space(3))) void*)l,
                                     16, 0, 0);
}

// ---- fp32 (768 x C) -> bf16 (C x 768) transpose, generic (for W_merge) -----
__global__ void k_tcvt(const float* __restrict__ src,
                       __bf16* __restrict__ dst, int R, int C) {
    __shared__ __bf16 tile[32][33];
    int tx = threadIdx.x, ty = threadIdx.y;
    int x = blockIdx.x * 32 + tx;
    int y = blockIdx.y * 32 + ty;
#pragma unroll
    for (int j = 0; j < 32; j += 8)
        tile[ty + j][tx] = (__bf16)src[(size_t)(y + j) * C + x];
    __syncthreads();
    int x2 = blockIdx.y * 32 + tx;
    int y2 = blockIdx.x * 32 + ty;
#pragma unroll
    for (int j = 0; j < 32; j += 8)
        dst[(size_t)(y2 + j) * R + x2] = tile[tx][ty + j];
}

// ---- W_qkv transpose with column sort: dst row n = [region|h|v], src col f --
// n in [0,2304): region r=n/768, idx=n%768, h=idx>>6, v=idx&63 -> f=h*192+v*3+r
__global__ void k_tcvt_qkv(const float* __restrict__ src,   // (768 x 2304)
                           __bf16* __restrict__ dst) {      // (2304 x 768)
    __shared__ __bf16 tile[32][33];
    int tx = threadIdx.x, ty = threadIdx.y;
    int n = blockIdx.x * 32 + tx;
    int r = n / 768, idx = n - r * 768;
    int f = (idx >> 6) * 192 + (idx & 63) * 3 + r;
    int t0 = blockIdx.y * 32;
#pragma unroll
    for (int j = 0; j < 32; j += 8)
        tile[ty + j][tx] = (__bf16)src[(size_t)(t0 + ty + j) * F3 + f];
    __syncthreads();
#pragma unroll
    for (int j = 0; j < 32; j += 8)
        dst[(size_t)(blockIdx.x * 32 + ty + j) * T_ + t0 + tx] = tile[tx][ty + j];
}

// ---------------- QKV GEMM R7 ------------------------------------------------
__global__ __launch_bounds__(256) void k_qkv(const float* __restrict__ X,
                                             const __bf16* __restrict__ Wt,  // sorted (2304x768)
                                             __bf16* __restrict__ Q,
                                             __bf16* __restrict__ K,
                                             __bf16* __restrict__ Vt) {
    __shared__ __align__(16) __bf16 LDSb[2 * 128 * 64];   // As | Bs, 32 KB
    __bf16* As = LDSb;
    __bf16* Bs = LDSb + 128 * 64;

    int tid  = threadIdx.x;
    int lane = tid & 63, wave = tid >> 6;
    int l16  = lane & 15, quad = lane >> 4;
    int wm = (wave >> 1) * 64, wn = (wave & 1) * 64;
    int brow = blockIdx.x / 18, bcol = blockIdx.x % 18;

    int ar = tid >> 1, ah = tid & 1;          // A: row, col-half(32 fp32)
    int bro = tid >> 3, bq = tid & 7;         // B: row-in-32-group, lds piece
    const float* Ag = X + (size_t)(brow * 128 + ar) * T_ + ah * 32;

    f32x4 acc[4][4];
#pragma unroll
    for (int i = 0; i < 4; i++)
#pragma unroll
        for (int j = 0; j < 4; j++) acc[i][j] = (f32x4){0.f, 0.f, 0.f, 0.f};

    for (int k0 = 0; k0 < T_; k0 += 64) {
        __syncthreads();
        // B: async 16B; physical slot bq holds logical piece bq^(n&7)
#pragma unroll
        for (int it = 0; it < 4; it++) {
            int n = it * 32 + bro;
            int gp = bq ^ (n & 7);
            gload16(Wt + (size_t)(bcol * 128 + n) * T_ + k0 + gp * 8,
                    Bs + n * 64 + bq * 8);
        }
        // A: fp32 load + cvt + swizzled ds_write_b128
        float4 f0[8];
#pragma unroll
        for (int i = 0; i < 8; i++) f0[i] = *(const float4*)(Ag + k0 + i * 4);
#pragma unroll
        for (int p2 = 0; p2 < 4; p2++) {
            bf16x8 v;
            float4 a = f0[p2 * 2], b = f0[p2 * 2 + 1];
            v[0] = (__bf16)a.x; v[1] = (__bf16)a.y; v[2] = (__bf16)a.z; v[3] = (__bf16)a.w;
            v[4] = (__bf16)b.x; v[5] = (__bf16)b.y; v[6] = (__bf16)b.z; v[7] = (__bf16)b.w;
            int lp = ah * 4 + p2;
            *(bf16x8*)&As[ar * 64 + ((lp ^ (ar & 7)) << 3)] = v;
        }
        __syncthreads();
#pragma unroll
        for (int ks = 0; ks < 2; ks++) {
            bf16x8 af[4], bfr[4];
#pragma unroll
            for (int i = 0; i < 4; i++) {
                int r = wm + i * 16 + l16;
                af[i] = *(const bf16x8*)&As[r * 64 + (((ks * 4 + quad) ^ (r & 7)) << 3)];
            }
#pragma unroll
            for (int j = 0; j < 4; j++) {
                int r = wn + j * 16 + l16;
                bfr[j] = *(const bf16x8*)&Bs[r * 64 + (((ks * 4 + quad) ^ (r & 7)) << 3)];
            }
#pragma unroll
            for (int i = 0; i < 4; i++)
#pragma unroll
                for (int j = 0; j < 4; j++)
                    acc[i][j] = __builtin_amdgcn_mfma_f32_16x16x32_bf16(
                        af[i], bfr[j], acc[i][j], 0, 0, 0);
        }
    }

    int region = bcol / 6;             // 0=Q, 1=K, 2=V (pure per block)
    int b  = brow >> 3;
    int p0 = (brow & 7) * 128;

    if (region < 2) {
        __bf16* D = region == 0 ? Q : K;
#pragma unroll
        for (int j = 0; j < 4; j++) {
            int idx = (bcol - region * 6) * 128 + wn + j * 16 + l16;
            int h = idx >> 6, v = idx & 63;
            __bf16* Dh = D + ((size_t)(b * H_ + h) * P_) * DV + v;
#pragma unroll
            for (int i = 0; i < 4; i++)
#pragma unroll
                for (int r = 0; r < 4; r++)
                    Dh[(size_t)(p0 + wm + i * 16 + quad * 4 + r) * DV] = (__bf16)acc[i][j][r];
        }
    } else {
        // V: transpose 128x128 tile through LDS (reuse LDSb), 16B stores to Vt
        __syncthreads();
#pragma unroll
        for (int j = 0; j < 4; j++) {
            int n_loc = wn + j * 16 + l16;
#pragma unroll
            for (int i = 0; i < 4; i++)
#pragma unroll
            for (int r = 0; r < 4; r++) {
                int m_loc = wm + i * 16 + quad * 4 + r;
                int phys  = (m_loc >> 3) ^ (n_loc & 15);
                LDSb[n_loc * 128 + phys * 8 + (m_loc & 7)] = (__bf16)acc[i][j][r];
            }
        }
        __syncthreads();
        int n_loc = tid >> 1, halfm = tid & 1;
        int idx = (bcol - 12) * 128 + n_loc;
        int h = idx >> 6, v = idx & 63;
        __bf16* Dh = Vt + ((size_t)(b * H_ + h) * DV + v) * P_ + p0 + halfm * 64;
#pragma unroll
        for (int i = 0; i < 8; i++) {
            int chunk = halfm * 8 + i;                 // m-chunk index (8 elems)
            int phys  = chunk ^ (n_loc & 15);
            bf16x8 val = *(const bf16x8*)&LDSb[n_loc * 128 + phys * 8];
            *(bf16x8*)(Dh + i * 8) = val;              // p = p0 + halfm*64 + i*8 ..
        }
    }
}

// ---------------- merge GEMM (unchanged R3 structure) ------------------------
__global__ __launch_bounds__(256) void k_merge(const __bf16* __restrict__ O,
                                               const __bf16* __restrict__ Wt,
                                               float* __restrict__ out) {
    __shared__ __align__(16) __bf16 As[128 * BK];
    __shared__ __align__(16) __bf16 Bs[128 * BK];
    int tid  = threadIdx.x;
    int lane = tid & 63, wave = tid >> 6;
    int l16  = lane & 15, quad = lane >> 4;
    int wm = (wave >> 1) * 64, wn = (wave & 1) * 64;
    int nblk = HD / 128;
    int brow = blockIdx.x / nblk, bcol = blockIdx.x % nblk;
    const __bf16* Ag = O  + (size_t)(brow * 128 + tid / 4) * HD + (tid & 3) * 8;
    const __bf16* Bg = Wt + (size_t)(bcol * 128 + tid / 4) * HD + (tid & 3) * 8;
    f32x4 acc[4][4];
#pragma unroll
    for (int i = 0; i < 4; i++)
#pragma unroll
        for (int j = 0; j < 4; j++) acc[i][j] = (f32x4){0.f, 0.f, 0.f, 0.f};
    for (int k0 = 0; k0 < HD; k0 += BK) {
        __syncthreads();
        gload16(Ag + k0,            As + tid * 8);
        gload16(Ag + k0 + 64 * HD,  As + 2048 + tid * 8);
        gload16(Bg + k0,            Bs + tid * 8);
        gload16(Bg + k0 + 64 * HD,  Bs + 2048 + tid * 8);
        __syncthreads();
        bf16x8 af[4], bfr[4];
#pragma unroll
        for (int i = 0; i < 4; i++) {
            af[i]  = *(const bf16x8*)&As[(wm + i * 16 + l16) * BK + quad * 8];
            bfr[i] = *(const bf16x8*)&Bs[(wn + i * 16 + l16) * BK + quad * 8];
        }
#pragma unroll
        for (int i = 0; i < 4; i++)
#pragma unroll
            for (int j = 0; j < 4; j++)
                acc[i][j] = __builtin_amdgcn_mfma_f32_16x16x32_bf16(
                    af[i], bfr[j], acc[i][j], 0, 0, 0);
    }
#pragma unroll
    for (int i = 0; i < 4; i++)
#pragma unroll
        for (int j = 0; j < 4; j++) {
            int col = bcol * 128 + wn + j * 16 + l16;
#pragma unroll
            for (int r = 0; r < 4; r++) {
                size_t row = (size_t)(brow * 128 + wm + i * 16 + quad * 4 + r);
                out[row * HD + col] = acc[i][j][r];
            }
        }
}

// ---------------- attention (unchanged R5) -----------------------------------
__global__ __launch_bounds__(256) void k_attn(const __bf16* __restrict__ Q,
                                              const __bf16* __restrict__ Kb,
                                              const __bf16* __restrict__ Vt,
                                              __bf16* __restrict__ O) {
    __shared__ __align__(16) __bf16 Ks[128 * 64];
    __shared__ __align__(16) __bf16 Vs[64 * 128];
    __shared__ __align__(16) __bf16 Pb[4][16 * 128];

    int tid  = threadIdx.x;
    int lane = tid & 63, wave = tid >> 6;
    int l16  = lane & 15, quad = lane >> 4;

    int bid = blockIdx.x;
    int xcd = bid & 7;
    int seq = bid >> 3;
    int bh  = xcd * 12 + (seq % 12);
    int qt  = seq / 12;
    int b   = bh / H_, h = bh % H_;

    const __bf16* Qb  = Q  + (size_t)bh * P_ * DV;
    const __bf16* Kbh = Kb + (size_t)bh * P_ * DV;
    const __bf16* Vbh = Vt + (size_t)bh * DV * P_;
    int m0 = qt * 64 + wave * 16;

    bf16x8 a0 = *(const bf16x8*)(Qb + (size_t)(m0 + l16) * DV + quad * 8);
    bf16x8 a1 = *(const bf16x8*)(Qb + (size_t)(m0 + l16) * DV + 32 + quad * 8);

    int lK = lane >> 3, qK = lane & 7;
    int lV = lane >> 4, qV = lane & 15;

    __bf16* Pw = &Pb[wave][0];
    float lsum[4] = {0.f, 0.f, 0.f, 0.f};
    f32x4 oacc[4] = {{0.f,0.f,0.f,0.f},{0.f,0.f,0.f,0.f},{0.f,0.f,0.f,0.f},{0.f,0.f,0.f,0.f}};
    const float c_exp = 0.125f * 1.44269504f;
    int swq = l16 & 7;

    for (int c = 0; c < P_; c += 128) {
        __syncthreads();
#pragma unroll
        for (int i = 0; i < 4; i++) {
            int t  = wave * 4 + i;
            int rK = t * 8 + lK;
            int jK = qK ^ (rK & 7);
            gload16(Kbh + (size_t)(c + rK) * DV + jK * 8, Ks + t * 512 + lane * 8);
            int rV = t * 4 + lV;
            int jV = qV ^ (rV & 15);
            gload16(Vbh + (size_t)rV * P_ + c + jV * 8,  Vs + t * 512 + lane * 8);
        }
        __syncthreads();

        f32x4 s[8];
#pragma unroll
        for (int ct = 0; ct < 8; ct++) {
            int R = ct * 16 + l16;
            bf16x8 b0 = *(const bf16x8*)&Ks[R * 64 + ((quad ^ swq) * 8)];
            bf16x8 b1 = *(const bf16x8*)&Ks[R * 64 + (((4 + quad) ^ swq) * 8)];
            f32x4 z = {0.f, 0.f, 0.f, 0.f};
            z = __builtin_amdgcn_mfma_f32_16x16x32_bf16(a0, b0, z, 0, 0, 0);
            s[ct] = __builtin_amdgcn_mfma_f32_16x16x32_bf16(a1, b1, z, 0, 0, 0);
        }

#pragma unroll
        for (int ct = 0; ct < 8; ct++) {
#pragma unroll
            for (int r = 0; r < 4; r++) {
                float e = exp2f(s[ct][r] * c_exp);
                lsum[r] += e;
                Pw[(ct >> 1) * 512 + (quad * 4 + r) * 32 + (ct & 1) * 16 + l16] = (__bf16)e;
            }
        }

#pragma unroll
        for (int ks = 0; ks < 4; ks++) {
            bf16x8 af = *(const bf16x8*)&Pw[ks * 512 + l16 * 32 + quad * 8];
#pragma unroll
            for (int n = 0; n < 4; n++) {
                int R = n * 16 + l16;
                bf16x8 bv = *(const bf16x8*)&Vs[R * 128 + (((ks * 4 + quad) ^ l16) * 8)];
                oacc[n] = __builtin_amdgcn_mfma_f32_16x16x32_bf16(af, bv, oacc[n], 0, 0, 0);
            }
        }
    }

#pragma unroll
    for (int r = 0; r < 4; r++) {
#pragma unroll
        for (int m = 1; m < 16; m <<= 1)
            lsum[r] += __shfl_xor(lsum[r], m, 64);
        lsum[r] = 1.0f / lsum[r];
    }

#pragma unroll
    for (int n = 0; n < 4; n++) {
#pragma unroll
        for (int r = 0; r < 4; r++) {
            int p = m0 + quad * 4 + r;
            O[((size_t)b * P_ + p) * HD + h * DV + n * 16 + l16] = (__bf16)(oacc[n][r] * lsum[r]);
        }
    }
}

extern "C" void kernel_launch(void* const* d_in, const int* in_sizes, int n_in,
                              void* d_out, int out_size, void* d_ws, size_t ws_size,
                              hipStream_t stream) {
    const float* x      = (const float*)d_in[0];
    const float* wqkv   = (const float*)d_in[1];
    const float* wmerge = (const float*)d_in[2];

    char* w = (char*)d_ws;
    __bf16* WqT = (__bf16*)w;  w += (size_t)F3 * T_ * 2;
    __bf16* WmT = (__bf16*)w;  w += (size_t)HD * T_ * 2;
    __bf16* Q   = (__bf16*)w;  w += (size_t)B_ * H_ * P_ * DV * 2;
    __bf16* K   = (__bf16*)w;  w += (size_t)B_ * H_ * P_ * DV * 2;
    __bf16* Vt  = (__bf16*)w;  w += (size_t)B_ * H_ * P_ * DV * 2;
    __bf16* O   = (__bf16*)w;

    dim3 tb(32, 8);
    hipLaunchKernelGGL(k_tcvt_qkv, dim3(F3 / 32, T_ / 32), tb, 0, stream, wqkv, WqT);
    hipLaunchKernelGGL(k_tcvt,     dim3(HD / 32, T_ / 32), tb, 0, stream, wmerge, WmT, T_, HD);

    hipLaunchKernelGGL(k_qkv, dim3((B_ * P_ / 128) * (F3 / 128)), dim3(256), 0, stream,
                       x, WqT, Q, K, Vt);

    hipLaunchKernelGGL(k_attn, dim3(B_ * H_ * (P_ / 64)), dim3(256), 0, stream,
                       Q, K, Vt, O);

    hipLaunchKernelGGL(k_merge, dim3((B_ * P_ / 128) * (HD / 128)), dim3(256), 0, stream,
                       O, WmT, (float*)d_out);
}

// Round 8
// 237.009 us; speedup vs baseline: 1.0212x; 1.0212x over previous
//
#include <hip/hip_runtime.h>
#include <hip/hip_bf16.h>
#include <math.h>

// MHSA, fp32 I/O, bf16 MFMA internally.
// R8 = R7 + XCD-pinned grid mapping for k_qkv and k_merge (all column-blocks of
// a row-strip on one XCD -> A-strip fetched once, not 8x). k_qkv: sorted weight
// columns, BK=64, XOR-swizzled LDS, in-kernel fp32->bf16 A staging, V epilogue
// transposed through LDS. attn unchanged from R5.

#define B_  8
#define P_  1024
#define T_  768
#define H_  12
#define DV  64
#define F3  2304   // 3*H*DV
#define HD  768    // H*DV
#define BK  32

typedef float  f32x4  __attribute__((ext_vector_type(4)));
typedef __bf16 bf16x4 __attribute__((ext_vector_type(4)));
typedef __bf16 bf16x8 __attribute__((ext_vector_type(8)));

__device__ __forceinline__ void gload16(const void* g, void* l) {
    __builtin_amdgcn_global_load_lds((const __attribute__((address_space(1))) void*)g,
                                     (__attribute__((address_space(3))) void*)l,
                                     16, 0, 0);
}

// ---- fp32 (768 x C) -> bf16 (C x 768) transpose, generic (for W_merge) -----
__global__ void k_tcvt(const float* __restrict__ src,
                       __bf16* __restrict__ dst, int R, int C) {
    __shared__ __bf16 tile[32][33];
    int tx = threadIdx.x, ty = threadIdx.y;
    int x = blockIdx.x * 32 + tx;
    int y = blockIdx.y * 32 + ty;
#pragma unroll
    for (int j = 0; j < 32; j += 8)
        tile[ty + j][tx] = (__bf16)src[(size_t)(y + j) * C + x];
    __syncthreads();
    int x2 = blockIdx.y * 32 + tx;
    int y2 = blockIdx.x * 32 + ty;
#pragma unroll
    for (int j = 0; j < 32; j += 8)
        dst[(size_t)(y2 + j) * R + x2] = tile[tx][ty + j];
}

// ---- W_qkv transpose with column sort: dst row n = [region|h|v], src col f --
__global__ void k_tcvt_qkv(const float* __restrict__ src,   // (768 x 2304)
                           __bf16* __restrict__ dst) {      // (2304 x 768)
    __shared__ __bf16 tile[32][33];
    int tx = threadIdx.x, ty = threadIdx.y;
    int n = blockIdx.x * 32 + tx;
    int r = n / 768, idx = n - r * 768;
    int f = (idx >> 6) * 192 + (idx & 63) * 3 + r;
    int t0 = blockIdx.y * 32;
#pragma unroll
    for (int j = 0; j < 32; j += 8)
        tile[ty + j][tx] = (__bf16)src[(size_t)(t0 + ty + j) * F3 + f];
    __syncthreads();
#pragma unroll
    for (int j = 0; j < 32; j += 8)
        dst[(size_t)(blockIdx.x * 32 + ty + j) * T_ + t0 + tx] = tile[tx][ty + j];
}

// ---------------- QKV GEMM R8 ------------------------------------------------
__global__ __launch_bounds__(256) void k_qkv(const float* __restrict__ X,
                                             const __bf16* __restrict__ Wt,  // sorted (2304x768)
                                             __bf16* __restrict__ Q,
                                             __bf16* __restrict__ K,
                                             __bf16* __restrict__ Vt) {
    __shared__ __align__(16) __bf16 LDSb[2 * 128 * 64];   // As | Bs, 32 KB
    __bf16* As = LDSb;
    __bf16* Bs = LDSb + 128 * 64;

    int tid  = threadIdx.x;
    int lane = tid & 63, wave = tid >> 6;
    int l16  = lane & 15, quad = lane >> 4;
    int wm = (wave >> 1) * 64, wn = (wave & 1) * 64;

    // XCD-pinned mapping: all 18 bcols of a brow on one XCD (bid&7 = XCD).
    int bid  = blockIdx.x;
    int xcd  = bid & 7;
    int seq  = bid >> 3;               // 0..143
    int brow = (seq / 18) * 8 + xcd;   // 0..63
    int bcol = seq % 18;

    int ar = tid >> 1, ah = tid & 1;          // A: row, col-half(32 fp32)
    int bro = tid >> 3, bq = tid & 7;         // B: row-in-32-group, lds piece
    const float* Ag = X + (size_t)(brow * 128 + ar) * T_ + ah * 32;

    f32x4 acc[4][4];
#pragma unroll
    for (int i = 0; i < 4; i++)
#pragma unroll
        for (int j = 0; j < 4; j++) acc[i][j] = (f32x4){0.f, 0.f, 0.f, 0.f};

    for (int k0 = 0; k0 < T_; k0 += 64) {
        __syncthreads();
        // B: async 16B; physical slot bq holds logical piece bq^(n&7)
#pragma unroll
        for (int it = 0; it < 4; it++) {
            int n = it * 32 + bro;
            int gp = bq ^ (n & 7);
            gload16(Wt + (size_t)(bcol * 128 + n) * T_ + k0 + gp * 8,
                    Bs + n * 64 + bq * 8);
        }
        // A: fp32 load + cvt + swizzled ds_write_b128
        float4 f0[8];
#pragma unroll
        for (int i = 0; i < 8; i++) f0[i] = *(const float4*)(Ag + k0 + i * 4);
#pragma unroll
        for (int p2 = 0; p2 < 4; p2++) {
            bf16x8 v;
            float4 a = f0[p2 * 2], b = f0[p2 * 2 + 1];
            v[0] = (__bf16)a.x; v[1] = (__bf16)a.y; v[2] = (__bf16)a.z; v[3] = (__bf16)a.w;
            v[4] = (__bf16)b.x; v[5] = (__bf16)b.y; v[6] = (__bf16)b.z; v[7] = (__bf16)b.w;
            int lp = ah * 4 + p2;
            *(bf16x8*)&As[ar * 64 + ((lp ^ (ar & 7)) << 3)] = v;
        }
        __syncthreads();
#pragma unroll
        for (int ks = 0; ks < 2; ks++) {
            bf16x8 af[4], bfr[4];
#pragma unroll
            for (int i = 0; i < 4; i++) {
                int r = wm + i * 16 + l16;
                af[i] = *(const bf16x8*)&As[r * 64 + (((ks * 4 + quad) ^ (r & 7)) << 3)];
            }
#pragma unroll
            for (int j = 0; j < 4; j++) {
                int r = wn + j * 16 + l16;
                bfr[j] = *(const bf16x8*)&Bs[r * 64 + (((ks * 4 + quad) ^ (r & 7)) << 3)];
            }
#pragma unroll
            for (int i = 0; i < 4; i++)
#pragma unroll
                for (int j = 0; j < 4; j++)
                    acc[i][j] = __builtin_amdgcn_mfma_f32_16x16x32_bf16(
                        af[i], bfr[j], acc[i][j], 0, 0, 0);
        }
    }

    int region = bcol / 6;             // 0=Q, 1=K, 2=V (pure per block)
    int b  = brow >> 3;
    int p0 = (brow & 7) * 128;

    if (region < 2) {
        __bf16* D = region == 0 ? Q : K;
#pragma unroll
        for (int j = 0; j < 4; j++) {
            int idx = (bcol - region * 6) * 128 + wn + j * 16 + l16;
            int h = idx >> 6, v = idx & 63;
            __bf16* Dh = D + ((size_t)(b * H_ + h) * P_) * DV + v;
#pragma unroll
            for (int i = 0; i < 4; i++)
#pragma unroll
                for (int r = 0; r < 4; r++)
                    Dh[(size_t)(p0 + wm + i * 16 + quad * 4 + r) * DV] = (__bf16)acc[i][j][r];
        }
    } else {
        // V: transpose 128x128 tile through LDS (reuse LDSb), 16B stores to Vt
        __syncthreads();
#pragma unroll
        for (int j = 0; j < 4; j++) {
            int n_loc = wn + j * 16 + l16;
#pragma unroll
            for (int i = 0; i < 4; i++)
#pragma unroll
            for (int r = 0; r < 4; r++) {
                int m_loc = wm + i * 16 + quad * 4 + r;
                int phys  = (m_loc >> 3) ^ (n_loc & 15);
                LDSb[n_loc * 128 + phys * 8 + (m_loc & 7)] = (__bf16)acc[i][j][r];
            }
        }
        __syncthreads();
        int n_loc = tid >> 1, halfm = tid & 1;
        int idx = (bcol - 12) * 128 + n_loc;
        int h = idx >> 6, v = idx & 63;
        __bf16* Dh = Vt + ((size_t)(b * H_ + h) * DV + v) * P_ + p0 + halfm * 64;
#pragma unroll
        for (int i = 0; i < 8; i++) {
            int chunk = halfm * 8 + i;
            int phys  = chunk ^ (n_loc & 15);
            bf16x8 val = *(const bf16x8*)&LDSb[n_loc * 128 + phys * 8];
            *(bf16x8*)(Dh + i * 8) = val;
        }
    }
}

// ---------------- merge GEMM (R3 structure + XCD pinning) --------------------
__global__ __launch_bounds__(256) void k_merge(const __bf16* __restrict__ O,
                                               const __bf16* __restrict__ Wt,
                                               float* __restrict__ out) {
    __shared__ __align__(16) __bf16 As[128 * BK];
    __shared__ __align__(16) __bf16 Bs[128 * BK];
    int tid  = threadIdx.x;
    int lane = tid & 63, wave = tid >> 6;
    int l16  = lane & 15, quad = lane >> 4;
    int wm = (wave >> 1) * 64, wn = (wave & 1) * 64;

    int bid  = blockIdx.x;
    int xcd  = bid & 7;
    int seq  = bid >> 3;               // 0..47
    int brow = (seq / 6) * 8 + xcd;    // 0..63
    int bcol = seq % 6;

    const __bf16* Ag = O  + (size_t)(brow * 128 + tid / 4) * HD + (tid & 3) * 8;
    const __bf16* Bg = Wt + (size_t)(bcol * 128 + tid / 4) * HD + (tid & 3) * 8;
    f32x4 acc[4][4];
#pragma unroll
    for (int i = 0; i < 4; i++)
#pragma unroll
        for (int j = 0; j < 4; j++) acc[i][j] = (f32x4){0.f, 0.f, 0.f, 0.f};
    for (int k0 = 0; k0 < HD; k0 += BK) {
        __syncthreads();
        gload16(Ag + k0,            As + tid * 8);
        gload16(Ag + k0 + 64 * HD,  As + 2048 + tid * 8);
        gload16(Bg + k0,            Bs + tid * 8);
        gload16(Bg + k0 + 64 * HD,  Bs + 2048 + tid * 8);
        __syncthreads();
        bf16x8 af[4], bfr[4];
#pragma unroll
        for (int i = 0; i < 4; i++) {
            af[i]  = *(const bf16x8*)&As[(wm + i * 16 + l16) * BK + quad * 8];
            bfr[i] = *(const bf16x8*)&Bs[(wn + i * 16 + l16) * BK + quad * 8];
        }
#pragma unroll
        for (int i = 0; i < 4; i++)
#pragma unroll
            for (int j = 0; j < 4; j++)
                acc[i][j] = __builtin_amdgcn_mfma_f32_16x16x32_bf16(
                    af[i], bfr[j], acc[i][j], 0, 0, 0);
    }
#pragma unroll
    for (int i = 0; i < 4; i++)
#pragma unroll
        for (int j = 0; j < 4; j++) {
            int col = bcol * 128 + wn + j * 16 + l16;
#pragma unroll
            for (int r = 0; r < 4; r++) {
                size_t row = (size_t)(brow * 128 + wm + i * 16 + quad * 4 + r);
                out[row * HD + col] = acc[i][j][r];
            }
        }
}

// ---------------- attention (unchanged R5) -----------------------------------
__global__ __launch_bounds__(256) void k_attn(const __bf16* __restrict__ Q,
                                              const __bf16* __restrict__ Kb,
                                              const __bf16* __restrict__ Vt,
                                              __bf16* __restrict__ O) {
    __shared__ __align__(16) __bf16 Ks[128 * 64];
    __shared__ __align__(16) __bf16 Vs[64 * 128];
    __shared__ __align__(16) __bf16 Pb[4][16 * 128];

    int tid  = threadIdx.x;
    int lane = tid & 63, wave = tid >> 6;
    int l16  = lane & 15, quad = lane >> 4;

    int bid = blockIdx.x;
    int xcd = bid & 7;
    int seq = bid >> 3;
    int bh  = xcd * 12 + (seq % 12);
    int qt  = seq / 12;
    int b   = bh / H_, h = bh % H_;

    const __bf16* Qb  = Q  + (size_t)bh * P_ * DV;
    const __bf16* Kbh = Kb + (size_t)bh * P_ * DV;
    const __bf16* Vbh = Vt + (size_t)bh * DV * P_;
    int m0 = qt * 64 + wave * 16;

    bf16x8 a0 = *(const bf16x8*)(Qb + (size_t)(m0 + l16) * DV + quad * 8);
    bf16x8 a1 = *(const bf16x8*)(Qb + (size_t)(m0 + l16) * DV + 32 + quad * 8);

    int lK = lane >> 3, qK = lane & 7;
    int lV = lane >> 4, qV = lane & 15;

    __bf16* Pw = &Pb[wave][0];
    float lsum[4] = {0.f, 0.f, 0.f, 0.f};
    f32x4 oacc[4] = {{0.f,0.f,0.f,0.f},{0.f,0.f,0.f,0.f},{0.f,0.f,0.f,0.f},{0.f,0.f,0.f,0.f}};
    const float c_exp = 0.125f * 1.44269504f;
    int swq = l16 & 7;

    for (int c = 0; c < P_; c += 128) {
        __syncthreads();
#pragma unroll
        for (int i = 0; i < 4; i++) {
            int t  = wave * 4 + i;
            int rK = t * 8 + lK;
            int jK = qK ^ (rK & 7);
            gload16(Kbh + (size_t)(c + rK) * DV + jK * 8, Ks + t * 512 + lane * 8);
            int rV = t * 4 + lV;
            int jV = qV ^ (rV & 15);
            gload16(Vbh + (size_t)rV * P_ + c + jV * 8,  Vs + t * 512 + lane * 8);
        }
        __syncthreads();

        f32x4 s[8];
#pragma unroll
        for (int ct = 0; ct < 8; ct++) {
            int R = ct * 16 + l16;
            bf16x8 b0 = *(const bf16x8*)&Ks[R * 64 + ((quad ^ swq) * 8)];
            bf16x8 b1 = *(const bf16x8*)&Ks[R * 64 + (((4 + quad) ^ swq) * 8)];
            f32x4 z = {0.f, 0.f, 0.f, 0.f};
            z = __builtin_amdgcn_mfma_f32_16x16x32_bf16(a0, b0, z, 0, 0, 0);
            s[ct] = __builtin_amdgcn_mfma_f32_16x16x32_bf16(a1, b1, z, 0, 0, 0);
        }

#pragma unroll
        for (int ct = 0; ct < 8; ct++) {
#pragma unroll
            for (int r = 0; r < 4; r++) {
                float e = exp2f(s[ct][r] * c_exp);
                lsum[r] += e;
                Pw[(ct >> 1) * 512 + (quad * 4 + r) * 32 + (ct & 1) * 16 + l16] = (__bf16)e;
            }
        }

#pragma unroll
        for (int ks = 0; ks < 4; ks++) {
            bf16x8 af = *(const bf16x8*)&Pw[ks * 512 + l16 * 32 + quad * 8];
#pragma unroll
            for (int n = 0; n < 4; n++) {
                int R = n * 16 + l16;
                bf16x8 bv = *(const bf16x8*)&Vs[R * 128 + (((ks * 4 + quad) ^ l16) * 8)];
                oacc[n] = __builtin_amdgcn_mfma_f32_16x16x32_bf16(af, bv, oacc[n], 0, 0, 0);
            }
        }
    }

#pragma unroll
    for (int r = 0; r < 4; r++) {
#pragma unroll
        for (int m = 1; m < 16; m <<= 1)
            lsum[r] += __shfl_xor(lsum[r], m, 64);
        lsum[r] = 1.0f / lsum[r];
    }

#pragma unroll
    for (int n = 0; n < 4; n++) {
#pragma unroll
        for (int r = 0; r < 4; r++) {
            int p = m0 + quad * 4 + r;
            O[((size_t)b * P_ + p) * HD + h * DV + n * 16 + l16] = (__bf16)(oacc[n][r] * lsum[r]);
        }
    }
}

extern "C" void kernel_launch(void* const* d_in, const int* in_sizes, int n_in,
                              void* d_out, int out_size, void* d_ws, size_t ws_size,
                              hipStream_t stream) {
    const float* x      = (const float*)d_in[0];
    const float* wqkv   = (const float*)d_in[1];
    const float* wmerge = (const float*)d_in[2];

    char* w = (char*)d_ws;
    __bf16* WqT = (__bf16*)w;  w += (size_t)F3 * T_ * 2;
    __bf16* WmT = (__bf16*)w;  w += (size_t)HD * T_ * 2;
    __bf16* Q   = (__bf16*)w;  w += (size_t)B_ * H_ * P_ * DV * 2;
    __bf16* K   = (__bf16*)w;  w += (size_t)B_ * H_ * P_ * DV * 2;
    __bf16* Vt  = (__bf16*)w;  w += (size_t)B_ * H_ * P_ * DV * 2;
    __bf16* O   = (__bf16*)w;

    dim3 tb(32, 8);
    hipLaunchKernelGGL(k_tcvt_qkv, dim3(F3 / 32, T_ / 32), tb, 0, stream, wqkv, WqT);
    hipLaunchKernelGGL(k_tcvt,     dim3(HD / 32, T_ / 32), tb, 0, stream, wmerge, WmT, T_, HD);

    hipLaunchKernelGGL(k_qkv, dim3((B_ * P_ / 128) * (F3 / 128)), dim3(256), 0, stream,
                       x, WqT, Q, K, Vt);

    hipLaunchKernelGGL(k_attn, dim3(B_ * H_ * (P_ / 64)), dim3(256), 0, stream,
                       Q, K, Vt, O);

    hipLaunchKernelGGL(k_merge, dim3((B_ * P_ / 128) * (HD / 128)), dim3(256), 0, stream,
                       O, WmT, (float*)d_out);
}

// Round 9
// 209.716 us; speedup vs baseline: 1.1541x; 1.1301x over previous
//
#include <hip/hip_runtime.h>
#include <hip/hip_bf16.h>
#include <math.h>

// MHSA, fp32 I/O, bf16 MFMA internally.
// R9: k_qkv back to pure global_load_lds staging (bf16 Xb from a separate
// XCD-affine cvt kernel) — R8's in-kernel fp32 A-path cost occupancy/MFMA util.
// BK=64 + XOR-swizzled LDS + XCD pinning + sorted weights kept. k_merge
// upgraded to the same BK=64 swizzled mainloop. attn unchanged from R5.

#define B_  8
#define P_  1024
#define T_  768
#define H_  12
#define DV  64
#define F3  2304   // 3*H*DV
#define HD  768    // H*DV

typedef float  f32x4  __attribute__((ext_vector_type(4)));
typedef __bf16 bf16x4 __attribute__((ext_vector_type(4)));
typedef __bf16 bf16x8 __attribute__((ext_vector_type(8)));

__device__ __forceinline__ void gload16(const void* g, void* l) {
    __builtin_amdgcn_global_load_lds((const __attribute__((address_space(1))) void*)g,
                                     (__attribute__((address_space(3))) void*)l,
                                     16, 0, 0);
}

// ---- X fp32 -> bf16, XCD-affine: strip brow (128 rows) written by XCD brow%8
__global__ __launch_bounds__(256) void k_cvt(const float* __restrict__ src,
                                             __bf16* __restrict__ dst) {
    int bid = blockIdx.x;                 // 768 blocks: 64 strips x 12
    int xcd = bid & 7;
    int seq = bid >> 3;                   // 0..95
    int strip = (seq / 12) * 8 + xcd;     // 0..63
    int sub   = seq % 12;
    size_t base = (size_t)strip * (128 * T_) + (size_t)sub * (128 * T_ / 12);
    const float4* s4 = (const float4*)(src + base);
    bf16x4*       d4 = (bf16x4*)(dst + base);
#pragma unroll
    for (int i = 0; i < 8; i++) {         // 2048 float4 per block
        float4 v = s4[i * 256 + threadIdx.x];
        bf16x4 o = { (__bf16)v.x, (__bf16)v.y, (__bf16)v.z, (__bf16)v.w };
        d4[i * 256 + threadIdx.x] = o;
    }
}

// ---- fp32 (768 x C) -> bf16 (C x 768) transpose, generic (for W_merge) -----
__global__ void k_tcvt(const float* __restrict__ src,
                       __bf16* __restrict__ dst, int R, int C) {
    __shared__ __bf16 tile[32][33];
    int tx = threadIdx.x, ty = threadIdx.y;
    int x = blockIdx.x * 32 + tx;
    int y = blockIdx.y * 32 + ty;
#pragma unroll
    for (int j = 0; j < 32; j += 8)
        tile[ty + j][tx] = (__bf16)src[(size_t)(y + j) * C + x];
    __syncthreads();
    int x2 = blockIdx.y * 32 + tx;
    int y2 = blockIdx.x * 32 + ty;
#pragma unroll
    for (int j = 0; j < 32; j += 8)
        dst[(size_t)(y2 + j) * R + x2] = tile[tx][ty + j];
}

// ---- W_qkv transpose with column sort: dst row n = [region|h|v], src col f --
__global__ void k_tcvt_qkv(const float* __restrict__ src,   // (768 x 2304)
                           __bf16* __restrict__ dst) {      // (2304 x 768)
    __shared__ __bf16 tile[32][33];
    int tx = threadIdx.x, ty = threadIdx.y;
    int n = blockIdx.x * 32 + tx;
    int r = n / 768, idx = n - r * 768;
    int f = (idx >> 6) * 192 + (idx & 63) * 3 + r;
    int t0 = blockIdx.y * 32;
#pragma unroll
    for (int j = 0; j < 32; j += 8)
        tile[ty + j][tx] = (__bf16)src[(size_t)(t0 + ty + j) * F3 + f];
    __syncthreads();
#pragma unroll
    for (int j = 0; j < 32; j += 8)
        dst[(size_t)(blockIdx.x * 32 + ty + j) * T_ + t0 + tx] = tile[tx][ty + j];
}

// ---- shared BK=64 swizzled mainloop: A(Mx768 row-major bf16), Bt(Nx768) -----
// Staged via global_load_lds; physical 16B slot q of LDS row n holds logical
// piece q^(n&7); frag reads XOR back -> 2-way-max bank aliasing.
#define GEMM64_MAINLOOP(Aptr, Btptr, brow, bcol, LD)                             \
    int tid  = threadIdx.x;                                                      \
    int lane = tid & 63, wave = tid >> 6;                                        \
    int l16  = lane & 15, quad = lane >> 4;                                      \
    int wm = (wave >> 1) * 64, wn = (wave & 1) * 64;                             \
    int bro = tid >> 3, bq = tid & 7;                                            \
    f32x4 acc[4][4];                                                             \
    _Pragma("unroll") for (int i = 0; i < 4; i++)                                \
        _Pragma("unroll") for (int j = 0; j < 4; j++)                            \
            acc[i][j] = (f32x4){0.f, 0.f, 0.f, 0.f};                             \
    for (int k0 = 0; k0 < (LD); k0 += 64) {                                      \
        __syncthreads();                                                         \
        _Pragma("unroll") for (int it = 0; it < 4; it++) {                       \
            int n = it * 32 + bro;                                               \
            int gp = bq ^ (n & 7);                                               \
            gload16((Aptr) + (size_t)((brow) * 128 + n) * (LD) + k0 + gp * 8,    \
                    As + it * 2048 + tid * 8);                                   \
            gload16((Btptr) + (size_t)((bcol) * 128 + n) * (LD) + k0 + gp * 8,   \
                    Bs + it * 2048 + tid * 8);                                   \
        }                                                                        \
        __syncthreads();                                                         \
        _Pragma("unroll") for (int ks = 0; ks < 2; ks++) {                       \
            bf16x8 af[4], bfr[4];                                                \
            _Pragma("unroll") for (int i = 0; i < 4; i++) {                      \
                int r = wm + i * 16 + l16;                                       \
                af[i] = *(const bf16x8*)&As[r * 64 + (((ks * 4 + quad) ^ (r & 7)) << 3)]; \
            }                                                                    \
            _Pragma("unroll") for (int j = 0; j < 4; j++) {                      \
                int r = wn + j * 16 + l16;                                       \
                bfr[j] = *(const bf16x8*)&Bs[r * 64 + (((ks * 4 + quad) ^ (r & 7)) << 3)]; \
            }                                                                    \
            _Pragma("unroll") for (int i = 0; i < 4; i++)                        \
                _Pragma("unroll") for (int j = 0; j < 4; j++)                    \
                    acc[i][j] = __builtin_amdgcn_mfma_f32_16x16x32_bf16(         \
                        af[i], bfr[j], acc[i][j], 0, 0, 0);                      \
        }                                                                        \
    }

// ---------------- QKV GEMM R9 ------------------------------------------------
__global__ __launch_bounds__(256) void k_qkv(const __bf16* __restrict__ Xb,
                                             const __bf16* __restrict__ Wt,  // sorted (2304x768)
                                             __bf16* __restrict__ Q,
                                             __bf16* __restrict__ K,
                                             __bf16* __restrict__ Vt) {
    __shared__ __align__(16) __bf16 LDSb[2 * 128 * 64];   // As | Bs, 32 KB
    __bf16* As = LDSb;
    __bf16* Bs = LDSb + 128 * 64;

    // XCD-pinned: all 18 bcols of a brow on one XCD (bid&7 = XCD).
    int bid  = blockIdx.x;
    int xcd  = bid & 7;
    int seq  = bid >> 3;               // 0..143
    int brow = (seq / 18) * 8 + xcd;   // 0..63
    int bcol = seq % 18;

    GEMM64_MAINLOOP(Xb, Wt, brow, bcol, T_)

    int region = bcol / 6;             // 0=Q, 1=K, 2=V (pure per block)
    int b  = brow >> 3;
    int p0 = (brow & 7) * 128;

    if (region < 2) {
        __bf16* D = region == 0 ? Q : K;
#pragma unroll
        for (int j = 0; j < 4; j++) {
            int idx = (bcol - region * 6) * 128 + wn + j * 16 + l16;
            int h = idx >> 6, v = idx & 63;
            __bf16* Dh = D + ((size_t)(b * H_ + h) * P_) * DV + v;
#pragma unroll
            for (int i = 0; i < 4; i++)
#pragma unroll
                for (int r = 0; r < 4; r++)
                    Dh[(size_t)(p0 + wm + i * 16 + quad * 4 + r) * DV] = (__bf16)acc[i][j][r];
        }
    } else {
        // V: transpose 128x128 tile through LDS (reuse LDSb), 16B stores to Vt
        __syncthreads();
#pragma unroll
        for (int j = 0; j < 4; j++) {
            int n_loc = wn + j * 16 + l16;
#pragma unroll
            for (int i = 0; i < 4; i++)
#pragma unroll
            for (int r = 0; r < 4; r++) {
                int m_loc = wm + i * 16 + quad * 4 + r;
                int phys  = (m_loc >> 3) ^ (n_loc & 15);
                LDSb[n_loc * 128 + phys * 8 + (m_loc & 7)] = (__bf16)acc[i][j][r];
            }
        }
        __syncthreads();
        int n_loc = tid >> 1, halfm = tid & 1;
        int idx = (bcol - 12) * 128 + n_loc;
        int h = idx >> 6, v = idx & 63;
        __bf16* Dh = Vt + ((size_t)(b * H_ + h) * DV + v) * P_ + p0 + halfm * 64;
#pragma unroll
        for (int i = 0; i < 8; i++) {
            int chunk = halfm * 8 + i;
            int phys  = chunk ^ (n_loc & 15);
            bf16x8 val = *(const bf16x8*)&LDSb[n_loc * 128 + phys * 8];
            *(bf16x8*)(Dh + i * 8) = val;
        }
    }
}

// ---------------- merge GEMM R9 (BK=64 swizzled, XCD-pinned) -----------------
__global__ __launch_bounds__(256) void k_merge(const __bf16* __restrict__ O,
                                               const __bf16* __restrict__ Wt,
                                               float* __restrict__ out) {
    __shared__ __align__(16) __bf16 LDSb[2 * 128 * 64];
    __bf16* As = LDSb;
    __bf16* Bs = LDSb + 128 * 64;

    int bid  = blockIdx.x;
    int xcd  = bid & 7;
    int seq  = bid >> 3;               // 0..47
    int brow = (seq / 6) * 8 + xcd;    // 0..63
    int bcol = seq % 6;

    GEMM64_MAINLOOP(O, Wt, brow, bcol, HD)

#pragma unroll
    for (int i = 0; i < 4; i++)
#pragma unroll
        for (int j = 0; j < 4; j++) {
            int col = bcol * 128 + wn + j * 16 + l16;
#pragma unroll
            for (int r = 0; r < 4; r++) {
                size_t row = (size_t)(brow * 128 + wm + i * 16 + quad * 4 + r);
                out[row * HD + col] = acc[i][j][r];
            }
        }
}

// ---------------- attention (unchanged R5) -----------------------------------
__global__ __launch_bounds__(256) void k_attn(const __bf16* __restrict__ Q,
                                              const __bf16* __restrict__ Kb,
                                              const __bf16* __restrict__ Vt,
                                              __bf16* __restrict__ O) {
    __shared__ __align__(16) __bf16 Ks[128 * 64];
    __shared__ __align__(16) __bf16 Vs[64 * 128];
    __shared__ __align__(16) __bf16 Pb[4][16 * 128];

    int tid  = threadIdx.x;
    int lane = tid & 63, wave = tid >> 6;
    int l16  = lane & 15, quad = lane >> 4;

    int bid = blockIdx.x;
    int xcd = bid & 7;
    int seq = bid >> 3;
    int bh  = xcd * 12 + (seq % 12);
    int qt  = seq / 12;
    int b   = bh / H_, h = bh % H_;

    const __bf16* Qb  = Q  + (size_t)bh * P_ * DV;
    const __bf16* Kbh = Kb + (size_t)bh * P_ * DV;
    const __bf16* Vbh = Vt + (size_t)bh * DV * P_;
    int m0 = qt * 64 + wave * 16;

    bf16x8 a0 = *(const bf16x8*)(Qb + (size_t)(m0 + l16) * DV + quad * 8);
    bf16x8 a1 = *(const bf16x8*)(Qb + (size_t)(m0 + l16) * DV + 32 + quad * 8);

    int lK = lane >> 3, qK = lane & 7;
    int lV = lane >> 4, qV = lane & 15;

    __bf16* Pw = &Pb[wave][0];
    float lsum[4] = {0.f, 0.f, 0.f, 0.f};
    f32x4 oacc[4] = {{0.f,0.f,0.f,0.f},{0.f,0.f,0.f,0.f},{0.f,0.f,0.f,0.f},{0.f,0.f,0.f,0.f}};
    const float c_exp = 0.125f * 1.44269504f;
    int swq = l16 & 7;

    for (int c = 0; c < P_; c += 128) {
        __syncthreads();
#pragma unroll
        for (int i = 0; i < 4; i++) {
            int t  = wave * 4 + i;
            int rK = t * 8 + lK;
            int jK = qK ^ (rK & 7);
            gload16(Kbh + (size_t)(c + rK) * DV + jK * 8, Ks + t * 512 + lane * 8);
            int rV = t * 4 + lV;
            int jV = qV ^ (rV & 15);
            gload16(Vbh + (size_t)rV * P_ + c + jV * 8,  Vs + t * 512 + lane * 8);
        }
        __syncthreads();

        f32x4 s[8];
#pragma unroll
        for (int ct = 0; ct < 8; ct++) {
            int R = ct * 16 + l16;
            bf16x8 b0 = *(const bf16x8*)&Ks[R * 64 + ((quad ^ swq) * 8)];
            bf16x8 b1 = *(const bf16x8*)&Ks[R * 64 + (((4 + quad) ^ swq) * 8)];
            f32x4 z = {0.f, 0.f, 0.f, 0.f};
            z = __builtin_amdgcn_mfma_f32_16x16x32_bf16(a0, b0, z, 0, 0, 0);
            s[ct] = __builtin_amdgcn_mfma_f32_16x16x32_bf16(a1, b1, z, 0, 0, 0);
        }

#pragma unroll
        for (int ct = 0; ct < 8; ct++) {
#pragma unroll
            for (int r = 0; r < 4; r++) {
                float e = exp2f(s[ct][r] * c_exp);
                lsum[r] += e;
                Pw[(ct >> 1) * 512 + (quad * 4 + r) * 32 + (ct & 1) * 16 + l16] = (__bf16)e;
            }
        }

#pragma unroll
        for (int ks = 0; ks < 4; ks++) {
            bf16x8 af = *(const bf16x8*)&Pw[ks * 512 + l16 * 32 + quad * 8];
#pragma unroll
            for (int n = 0; n < 4; n++) {
                int R = n * 16 + l16;
                bf16x8 bv = *(const bf16x8*)&Vs[R * 128 + (((ks * 4 + quad) ^ l16) * 8)];
                oacc[n] = __builtin_amdgcn_mfma_f32_16x16x32_bf16(af, bv, oacc[n], 0, 0, 0);
            }
        }
    }

#pragma unroll
    for (int r = 0; r < 4; r++) {
#pragma unroll
        for (int m = 1; m < 16; m <<= 1)
            lsum[r] += __shfl_xor(lsum[r], m, 64);
        lsum[r] = 1.0f / lsum[r];
    }

#pragma unroll
    for (int n = 0; n < 4; n++) {
#pragma unroll
        for (int r = 0; r < 4; r++) {
            int p = m0 + quad * 4 + r;
            O[((size_t)b * P_ + p) * HD + h * DV + n * 16 + l16] = (__bf16)(oacc[n][r] * lsum[r]);
        }
    }
}

extern "C" void kernel_launch(void* const* d_in, const int* in_sizes, int n_in,
                              void* d_out, int out_size, void* d_ws, size_t ws_size,
                              hipStream_t stream) {
    const float* x      = (const float*)d_in[0];
    const float* wqkv   = (const float*)d_in[1];
    const float* wmerge = (const float*)d_in[2];

    char* w = (char*)d_ws;
    __bf16* Xb  = (__bf16*)w;  w += (size_t)B_ * P_ * T_ * 2;
    __bf16* WqT = (__bf16*)w;  w += (size_t)F3 * T_ * 2;
    __bf16* WmT = (__bf16*)w;  w += (size_t)HD * T_ * 2;
    __bf16* Q   = (__bf16*)w;  w += (size_t)B_ * H_ * P_ * DV * 2;
    __bf16* K   = (__bf16*)w;  w += (size_t)B_ * H_ * P_ * DV * 2;
    __bf16* Vt  = (__bf16*)w;  w += (size_t)B_ * H_ * P_ * DV * 2;
    __bf16* O   = (__bf16*)w;

    hipLaunchKernelGGL(k_cvt, dim3(768), dim3(256), 0, stream, x, Xb);

    dim3 tb(32, 8);
    hipLaunchKernelGGL(k_tcvt_qkv, dim3(F3 / 32, T_ / 32), tb, 0, stream, wqkv, WqT);
    hipLaunchKernelGGL(k_tcvt,     dim3(HD / 32, T_ / 32), tb, 0, stream, wmerge, WmT, T_, HD);

    hipLaunchKernelGGL(k_qkv, dim3((B_ * P_ / 128) * (F3 / 128)), dim3(256), 0, stream,
                       Xb, WqT, Q, K, Vt);

    hipLaunchKernelGGL(k_attn, dim3(B_ * H_ * (P_ / 64)), dim3(256), 0, stream,
                       Q, K, Vt, O);

    hipLaunchKernelGGL(k_merge, dim3((B_ * P_ / 128) * (HD / 128)), dim3(256), 0, stream,
                       O, WmT, (float*)d_out);
}

// Round 10
// 204.980 us; speedup vs baseline: 1.1807x; 1.0231x over previous
//
#include <hip/hip_runtime.h>
#include <hip/hip_bf16.h>
#include <math.h>

// MHSA, fp32 I/O, bf16 MFMA internally.
// R10: k_attn computes S^T (swap MFMA operands) so the P LDS round-trip is
// vector-wide both sides: producer ds_write_b64 (4 packed keys @ fixed q),
// consumer ds_read_b128 (B-frag of O^T = Vt * P^T). Epilogue 8B stores.
// qkv/merge unchanged from R9.

#define B_  8
#define P_  1024
#define T_  768
#define H_  12
#define DV  64
#define F3  2304   // 3*H*DV
#define HD  768    // H*DV
#define PSTR 136   // P^T q-row stride in elems: 272 B = 17*16 -> b128-aligned, bank-rotating

typedef float  f32x4  __attribute__((ext_vector_type(4)));
typedef __bf16 bf16x4 __attribute__((ext_vector_type(4)));
typedef __bf16 bf16x8 __attribute__((ext_vector_type(8)));

__device__ __forceinline__ void gload16(const void* g, void* l) {
    __builtin_amdgcn_global_load_lds((const __attribute__((address_space(1))) void*)g,
                                     (__attribute__((address_space(3))) void*)l,
                                     16, 0, 0);
}

// ---- X fp32 -> bf16, XCD-affine ---------------------------------------------
__global__ __launch_bounds__(256) void k_cvt(const float* __restrict__ src,
                                             __bf16* __restrict__ dst) {
    int bid = blockIdx.x;
    int xcd = bid & 7;
    int seq = bid >> 3;
    int strip = (seq / 12) * 8 + xcd;
    int sub   = seq % 12;
    size_t base = (size_t)strip * (128 * T_) + (size_t)sub * (128 * T_ / 12);
    const float4* s4 = (const float4*)(src + base);
    bf16x4*       d4 = (bf16x4*)(dst + base);
#pragma unroll
    for (int i = 0; i < 8; i++) {
        float4 v = s4[i * 256 + threadIdx.x];
        bf16x4 o = { (__bf16)v.x, (__bf16)v.y, (__bf16)v.z, (__bf16)v.w };
        d4[i * 256 + threadIdx.x] = o;
    }
}

// ---- fp32 (768 x C) -> bf16 (C x 768) transpose (for W_merge) ---------------
__global__ void k_tcvt(const float* __restrict__ src,
                       __bf16* __restrict__ dst, int R, int C) {
    __shared__ __bf16 tile[32][33];
    int tx = threadIdx.x, ty = threadIdx.y;
    int x = blockIdx.x * 32 + tx;
    int y = blockIdx.y * 32 + ty;
#pragma unroll
    for (int j = 0; j < 32; j += 8)
        tile[ty + j][tx] = (__bf16)src[(size_t)(y + j) * C + x];
    __syncthreads();
    int x2 = blockIdx.y * 32 + tx;
    int y2 = blockIdx.x * 32 + ty;
#pragma unroll
    for (int j = 0; j < 32; j += 8)
        dst[(size_t)(y2 + j) * R + x2] = tile[tx][ty + j];
}

// ---- W_qkv transpose with column sort ---------------------------------------
__global__ void k_tcvt_qkv(const float* __restrict__ src,   // (768 x 2304)
                           __bf16* __restrict__ dst) {      // (2304 x 768)
    __shared__ __bf16 tile[32][33];
    int tx = threadIdx.x, ty = threadIdx.y;
    int n = blockIdx.x * 32 + tx;
    int r = n / 768, idx = n - r * 768;
    int f = (idx >> 6) * 192 + (idx & 63) * 3 + r;
    int t0 = blockIdx.y * 32;
#pragma unroll
    for (int j = 0; j < 32; j += 8)
        tile[ty + j][tx] = (__bf16)src[(size_t)(t0 + ty + j) * F3 + f];
    __syncthreads();
#pragma unroll
    for (int j = 0; j < 32; j += 8)
        dst[(size_t)(blockIdx.x * 32 + ty + j) * T_ + t0 + tx] = tile[tx][ty + j];
}

// ---- shared BK=64 swizzled mainloop (unchanged R9) --------------------------
#define GEMM64_MAINLOOP(Aptr, Btptr, brow, bcol, LD)                             \
    int tid  = threadIdx.x;                                                      \
    int lane = tid & 63, wave = tid >> 6;                                        \
    int l16  = lane & 15, quad = lane >> 4;                                      \
    int wm = (wave >> 1) * 64, wn = (wave & 1) * 64;                             \
    int bro = tid >> 3, bq = tid & 7;                                            \
    f32x4 acc[4][4];                                                             \
    _Pragma("unroll") for (int i = 0; i < 4; i++)                                \
        _Pragma("unroll") for (int j = 0; j < 4; j++)                            \
            acc[i][j] = (f32x4){0.f, 0.f, 0.f, 0.f};                             \
    for (int k0 = 0; k0 < (LD); k0 += 64) {                                      \
        __syncthreads();                                                         \
        _Pragma("unroll") for (int it = 0; it < 4; it++) {                       \
            int n = it * 32 + bro;                                               \
            int gp = bq ^ (n & 7);                                               \
            gload16((Aptr) + (size_t)((brow) * 128 + n) * (LD) + k0 + gp * 8,    \
                    As + it * 2048 + tid * 8);                                   \
            gload16((Btptr) + (size_t)((bcol) * 128 + n) * (LD) + k0 + gp * 8,   \
                    Bs + it * 2048 + tid * 8);                                   \
        }                                                                        \
        __syncthreads();                                                         \
        _Pragma("unroll") for (int ks = 0; ks < 2; ks++) {                       \
            bf16x8 af[4], bfr[4];                                                \
            _Pragma("unroll") for (int i = 0; i < 4; i++) {                      \
                int r = wm + i * 16 + l16;                                       \
                af[i] = *(const bf16x8*)&As[r * 64 + (((ks * 4 + quad) ^ (r & 7)) << 3)]; \
            }                                                                    \
            _Pragma("unroll") for (int j = 0; j < 4; j++) {                      \
                int r = wn + j * 16 + l16;                                       \
                bfr[j] = *(const bf16x8*)&Bs[r * 64 + (((ks * 4 + quad) ^ (r & 7)) << 3)]; \
            }                                                                    \
            _Pragma("unroll") for (int i = 0; i < 4; i++)                        \
                _Pragma("unroll") for (int j = 0; j < 4; j++)                    \
                    acc[i][j] = __builtin_amdgcn_mfma_f32_16x16x32_bf16(         \
                        af[i], bfr[j], acc[i][j], 0, 0, 0);                      \
        }                                                                        \
    }

// ---------------- QKV GEMM (unchanged R9) ------------------------------------
__global__ __launch_bounds__(256) void k_qkv(const __bf16* __restrict__ Xb,
                                             const __bf16* __restrict__ Wt,
                                             __bf16* __restrict__ Q,
                                             __bf16* __restrict__ K,
                                             __bf16* __restrict__ Vt) {
    __shared__ __align__(16) __bf16 LDSb[2 * 128 * 64];
    __bf16* As = LDSb;
    __bf16* Bs = LDSb + 128 * 64;

    int bid  = blockIdx.x;
    int xcd  = bid & 7;
    int seq  = bid >> 3;
    int brow = (seq / 18) * 8 + xcd;
    int bcol = seq % 18;

    GEMM64_MAINLOOP(Xb, Wt, brow, bcol, T_)

    int region = bcol / 6;
    int b  = brow >> 3;
    int p0 = (brow & 7) * 128;

    if (region < 2) {
        __bf16* D = region == 0 ? Q : K;
#pragma unroll
        for (int j = 0; j < 4; j++) {
            int idx = (bcol - region * 6) * 128 + wn + j * 16 + l16;
            int h = idx >> 6, v = idx & 63;
            __bf16* Dh = D + ((size_t)(b * H_ + h) * P_) * DV + v;
#pragma unroll
            for (int i = 0; i < 4; i++)
#pragma unroll
                for (int r = 0; r < 4; r++)
                    Dh[(size_t)(p0 + wm + i * 16 + quad * 4 + r) * DV] = (__bf16)acc[i][j][r];
        }
    } else {
        __syncthreads();
#pragma unroll
        for (int j = 0; j < 4; j++) {
            int n_loc = wn + j * 16 + l16;
#pragma unroll
            for (int i = 0; i < 4; i++)
#pragma unroll
            for (int r = 0; r < 4; r++) {
                int m_loc = wm + i * 16 + quad * 4 + r;
                int phys  = (m_loc >> 3) ^ (n_loc & 15);
                LDSb[n_loc * 128 + phys * 8 + (m_loc & 7)] = (__bf16)acc[i][j][r];
            }
        }
        __syncthreads();
        int n_loc = tid >> 1, halfm = tid & 1;
        int idx = (bcol - 12) * 128 + n_loc;
        int h = idx >> 6, v = idx & 63;
        __bf16* Dh = Vt + ((size_t)(b * H_ + h) * DV + v) * P_ + p0 + halfm * 64;
#pragma unroll
        for (int i = 0; i < 8; i++) {
            int chunk = halfm * 8 + i;
            int phys  = chunk ^ (n_loc & 15);
            bf16x8 val = *(const bf16x8*)&LDSb[n_loc * 128 + phys * 8];
            *(bf16x8*)(Dh + i * 8) = val;
        }
    }
}

// ---------------- merge GEMM (unchanged R9) ----------------------------------
__global__ __launch_bounds__(256) void k_merge(const __bf16* __restrict__ O,
                                               const __bf16* __restrict__ Wt,
                                               float* __restrict__ out) {
    __shared__ __align__(16) __bf16 LDSb[2 * 128 * 64];
    __bf16* As = LDSb;
    __bf16* Bs = LDSb + 128 * 64;

    int bid  = blockIdx.x;
    int xcd  = bid & 7;
    int seq  = bid >> 3;
    int brow = (seq / 6) * 8 + xcd;
    int bcol = seq % 6;

    GEMM64_MAINLOOP(O, Wt, brow, bcol, HD)

#pragma unroll
    for (int i = 0; i < 4; i++)
#pragma unroll
        for (int j = 0; j < 4; j++) {
            int col = bcol * 128 + wn + j * 16 + l16;
#pragma unroll
            for (int r = 0; r < 4; r++) {
                size_t row = (size_t)(brow * 128 + wm + i * 16 + quad * 4 + r);
                out[row * HD + col] = acc[i][j][r];
            }
        }
}

// ---------------- attention R10: S^T / O^T formulation -----------------------
__global__ __launch_bounds__(256) void k_attn(const __bf16* __restrict__ Q,
                                              const __bf16* __restrict__ Kb,
                                              const __bf16* __restrict__ Vt,
                                              __bf16* __restrict__ O) {
    __shared__ __align__(16) __bf16 Ks[128 * 64];         // 16 KB
    __shared__ __align__(16) __bf16 Vs[64 * 128];         // 16 KB
    __shared__ __align__(16) __bf16 Pb[4][16 * PSTR];     // P^T per wave: [q][key], 17 KB

    int tid  = threadIdx.x;
    int lane = tid & 63, wave = tid >> 6;
    int l16  = lane & 15, quad = lane >> 4;

    int bid = blockIdx.x;
    int xcd = bid & 7;
    int seq = bid >> 3;
    int bh  = xcd * 12 + (seq % 12);
    int qt  = seq / 12;
    int b   = bh / H_, h = bh % H_;

    const __bf16* Qb  = Q  + (size_t)bh * P_ * DV;
    const __bf16* Kbh = Kb + (size_t)bh * P_ * DV;
    const __bf16* Vbh = Vt + (size_t)bh * DV * P_;
    int m0 = qt * 64 + wave * 16;

    // Q fragments: B-operand of S^T MFMA needs B[k=t][n=q] = Q[q=m0+l16][t=quad*8+j]
    bf16x8 a0 = *(const bf16x8*)(Qb + (size_t)(m0 + l16) * DV + quad * 8);
    bf16x8 a1 = *(const bf16x8*)(Qb + (size_t)(m0 + l16) * DV + 32 + quad * 8);

    int lK = lane >> 3, qK = lane & 7;
    int lV = lane >> 4, qV = lane & 15;

    __bf16* Pw = &Pb[wave][0];
    float lsum = 0.f;
    f32x4 oacc[4] = {{0.f,0.f,0.f,0.f},{0.f,0.f,0.f,0.f},{0.f,0.f,0.f,0.f},{0.f,0.f,0.f,0.f}};
    const float c_exp = 0.125f * 1.44269504f;
    int swq = l16 & 7;

    for (int c = 0; c < P_; c += 128) {
        __syncthreads();
#pragma unroll
        for (int i = 0; i < 4; i++) {
            int t  = wave * 4 + i;
            int rK = t * 8 + lK;
            int jK = qK ^ (rK & 7);
            gload16(Kbh + (size_t)(c + rK) * DV + jK * 8, Ks + t * 512 + lane * 8);
            int rV = t * 4 + lV;
            int jV = qV ^ (rV & 15);
            gload16(Vbh + (size_t)rV * P_ + c + jV * 8,  Vs + t * 512 + lane * 8);
        }
        __syncthreads();

        // ---- S^T = K Q^T : s[ct][r] = S^T[key=ct*16+quad*4+r][q=m0+l16] ----
        f32x4 s[8];
#pragma unroll
        for (int ct = 0; ct < 8; ct++) {
            int R = ct * 16 + l16;    // key row in Ks (A-operand m)
            bf16x8 b0 = *(const bf16x8*)&Ks[R * 64 + ((quad ^ swq) * 8)];
            bf16x8 b1 = *(const bf16x8*)&Ks[R * 64 + (((4 + quad) ^ swq) * 8)];
            f32x4 z = {0.f, 0.f, 0.f, 0.f};
            z = __builtin_amdgcn_mfma_f32_16x16x32_bf16(b0, a0, z, 0, 0, 0);
            s[ct] = __builtin_amdgcn_mfma_f32_16x16x32_bf16(b1, a1, z, 0, 0, 0);
        }

        // ---- P^T: exp, pack 4 consecutive keys, one b64 write per tile ----
#pragma unroll
        for (int ct = 0; ct < 8; ct++) {
            bf16x4 pk;
#pragma unroll
            for (int r = 0; r < 4; r++) {
                float e = exp2f(s[ct][r] * c_exp);
                lsum += e;
                pk[r] = (__bf16)e;
            }
            *(bf16x4*)&Pw[l16 * PSTR + ct * 16 + quad * 4] = pk;
        }

        // ---- O^T += V_tile * P^T : A = Vs frag (m=d), B = P^T frag (n=q) ----
#pragma unroll
        for (int ks = 0; ks < 4; ks++) {
            bf16x8 pfrag = *(const bf16x8*)&Pw[l16 * PSTR + ks * 32 + quad * 8];
#pragma unroll
            for (int nt = 0; nt < 4; nt++) {
                int R = nt * 16 + l16;
                bf16x8 av = *(const bf16x8*)&Vs[R * 128 + (((ks * 4 + quad) ^ l16) * 8)];
                oacc[nt] = __builtin_amdgcn_mfma_f32_16x16x32_bf16(av, pfrag, oacc[nt], 0, 0, 0);
            }
        }
    }

    // row sum for q=m0+l16: reduce across the 4 quads holding this q
    lsum += __shfl_xor(lsum, 16, 64);
    lsum += __shfl_xor(lsum, 32, 64);
    float inv = 1.0f / lsum;

    // epilogue: oacc[nt][r] = O^T[d=nt*16+quad*4+r][q] -> O[b][p=q][h*64+d], 8B stores
    int p = m0 + l16;
    __bf16* Orow = O + ((size_t)b * P_ + p) * HD + h * DV;
#pragma unroll
    for (int nt = 0; nt < 4; nt++) {
        bf16x4 o4;
#pragma unroll
        for (int r = 0; r < 4; r++) o4[r] = (__bf16)(oacc[nt][r] * inv);
        *(bf16x4*)&Orow[nt * 16 + quad * 4] = o4;
    }
}

extern "C" void kernel_launch(void* const* d_in, const int* in_sizes, int n_in,
                              void* d_out, int out_size, void* d_ws, size_t ws_size,
                              hipStream_t stream) {
    const float* x      = (const float*)d_in[0];
    const float* wqkv   = (const float*)d_in[1];
    const float* wmerge = (const float*)d_in[2];

    char* w = (char*)d_ws;
    __bf16* Xb  = (__bf16*)w;  w += (size_t)B_ * P_ * T_ * 2;
    __bf16* WqT = (__bf16*)w;  w += (size_t)F3 * T_ * 2;
    __bf16* WmT = (__bf16*)w;  w += (size_t)HD * T_ * 2;
    __bf16* Q   = (__bf16*)w;  w += (size_t)B_ * H_ * P_ * DV * 2;
    __bf16* K   = (__bf16*)w;  w += (size_t)B_ * H_ * P_ * DV * 2;
    __bf16* Vt  = (__bf16*)w;  w += (size_t)B_ * H_ * P_ * DV * 2;
    __bf16* O   = (__bf16*)w;

    hipLaunchKernelGGL(k_cvt, dim3(768), dim3(256), 0, stream, x, Xb);

    dim3 tb(32, 8);
    hipLaunchKernelGGL(k_tcvt_qkv, dim3(F3 / 32, T_ / 32), tb, 0, stream, wqkv, WqT);
    hipLaunchKernelGGL(k_tcvt,     dim3(HD / 32, T_ / 32), tb, 0, stream, wmerge, WmT, T_, HD);

    hipLaunchKernelGGL(k_qkv, dim3((B_ * P_ / 128) * (F3 / 128)), dim3(256), 0, stream,
                       Xb, WqT, Q, K, Vt);

    hipLaunchKernelGGL(k_attn, dim3(B_ * H_ * (P_ / 64)), dim3(256), 0, stream,
                       Q, K, Vt, O);

    hipLaunchKernelGGL(k_merge, dim3((B_ * P_ / 128) * (HD / 128)), dim3(256), 0, stream,
                       O, WmT, (float*)d_out);
}

// Round 11
// 202.329 us; speedup vs baseline: 1.1962x; 1.0131x over previous
//
#include <hip/hip_runtime.h>
#include <hip/hip_bf16.h>
#include <math.h>

// MHSA, fp32 I/O, bf16 MFMA internally.
// R11: attn VALU diet — Q pre-scaled by 0.125*log2e in k_qkv epilogue (raw
// exp2f in the hot loop), row-sums via ones-MFMA (facc) instead of 32 VALU
// adds + shuffles. Rest unchanged from R10.

#define B_  8
#define P_  1024
#define T_  768
#define H_  12
#define DV  64
#define F3  2304   // 3*H*DV
#define HD  768    // H*DV
#define PSTR 136   // P^T q-row stride in elems: 272 B -> b128-aligned, bank-rotating

typedef float  f32x4  __attribute__((ext_vector_type(4)));
typedef __bf16 bf16x4 __attribute__((ext_vector_type(4)));
typedef __bf16 bf16x8 __attribute__((ext_vector_type(8)));

__device__ __forceinline__ void gload16(const void* g, void* l) {
    __builtin_amdgcn_global_load_lds((const __attribute__((address_space(1))) void*)g,
                                     (__attribute__((address_space(3))) void*)l,
                                     16, 0, 0);
}

// ---- X fp32 -> bf16, XCD-affine ---------------------------------------------
__global__ __launch_bounds__(256) void k_cvt(const float* __restrict__ src,
                                             __bf16* __restrict__ dst) {
    int bid = blockIdx.x;
    int xcd = bid & 7;
    int seq = bid >> 3;
    int strip = (seq / 12) * 8 + xcd;
    int sub   = seq % 12;
    size_t base = (size_t)strip * (128 * T_) + (size_t)sub * (128 * T_ / 12);
    const float4* s4 = (const float4*)(src + base);
    bf16x4*       d4 = (bf16x4*)(dst + base);
#pragma unroll
    for (int i = 0; i < 8; i++) {
        float4 v = s4[i * 256 + threadIdx.x];
        bf16x4 o = { (__bf16)v.x, (__bf16)v.y, (__bf16)v.z, (__bf16)v.w };
        d4[i * 256 + threadIdx.x] = o;
    }
}

// ---- fp32 (768 x C) -> bf16 (C x 768) transpose (for W_merge) ---------------
__global__ void k_tcvt(const float* __restrict__ src,
                       __bf16* __restrict__ dst, int R, int C) {
    __shared__ __bf16 tile[32][33];
    int tx = threadIdx.x, ty = threadIdx.y;
    int x = blockIdx.x * 32 + tx;
    int y = blockIdx.y * 32 + ty;
#pragma unroll
    for (int j = 0; j < 32; j += 8)
        tile[ty + j][tx] = (__bf16)src[(size_t)(y + j) * C + x];
    __syncthreads();
    int x2 = blockIdx.y * 32 + tx;
    int y2 = blockIdx.x * 32 + ty;
#pragma unroll
    for (int j = 0; j < 32; j += 8)
        dst[(size_t)(y2 + j) * R + x2] = tile[tx][ty + j];
}

// ---- W_qkv transpose with column sort ---------------------------------------
__global__ void k_tcvt_qkv(const float* __restrict__ src,   // (768 x 2304)
                           __bf16* __restrict__ dst) {      // (2304 x 768)
    __shared__ __bf16 tile[32][33];
    int tx = threadIdx.x, ty = threadIdx.y;
    int n = blockIdx.x * 32 + tx;
    int r = n / 768, idx = n - r * 768;
    int f = (idx >> 6) * 192 + (idx & 63) * 3 + r;
    int t0 = blockIdx.y * 32;
#pragma unroll
    for (int j = 0; j < 32; j += 8)
        tile[ty + j][tx] = (__bf16)src[(size_t)(t0 + ty + j) * F3 + f];
    __syncthreads();
#pragma unroll
    for (int j = 0; j < 32; j += 8)
        dst[(size_t)(blockIdx.x * 32 + ty + j) * T_ + t0 + tx] = tile[tx][ty + j];
}

// ---- shared BK=64 swizzled mainloop (unchanged R9) --------------------------
#define GEMM64_MAINLOOP(Aptr, Btptr, brow, bcol, LD)                             \
    int tid  = threadIdx.x;                                                      \
    int lane = tid & 63, wave = tid >> 6;                                        \
    int l16  = lane & 15, quad = lane >> 4;                                      \
    int wm = (wave >> 1) * 64, wn = (wave & 1) * 64;                             \
    int bro = tid >> 3, bq = tid & 7;                                            \
    f32x4 acc[4][4];                                                             \
    _Pragma("unroll") for (int i = 0; i < 4; i++)                                \
        _Pragma("unroll") for (int j = 0; j < 4; j++)                            \
            acc[i][j] = (f32x4){0.f, 0.f, 0.f, 0.f};                             \
    for (int k0 = 0; k0 < (LD); k0 += 64) {                                      \
        __syncthreads();                                                         \
        _Pragma("unroll") for (int it = 0; it < 4; it++) {                       \
            int n = it * 32 + bro;                                               \
            int gp = bq ^ (n & 7);                                               \
            gload16((Aptr) + (size_t)((brow) * 128 + n) * (LD) + k0 + gp * 8,    \
                    As + it * 2048 + tid * 8);                                   \
            gload16((Btptr) + (size_t)((bcol) * 128 + n) * (LD) + k0 + gp * 8,   \
                    Bs + it * 2048 + tid * 8);                                   \
        }                                                                        \
        __syncthreads();                                                         \
        _Pragma("unroll") for (int ks = 0; ks < 2; ks++) {                       \
            bf16x8 af[4], bfr[4];                                                \
            _Pragma("unroll") for (int i = 0; i < 4; i++) {                      \
                int r = wm + i * 16 + l16;                                       \
                af[i] = *(const bf16x8*)&As[r * 64 + (((ks * 4 + quad) ^ (r & 7)) << 3)]; \
            }                                                                    \
            _Pragma("unroll") for (int j = 0; j < 4; j++) {                      \
                int r = wn + j * 16 + l16;                                       \
                bfr[j] = *(const bf16x8*)&Bs[r * 64 + (((ks * 4 + quad) ^ (r & 7)) << 3)]; \
            }                                                                    \
            _Pragma("unroll") for (int i = 0; i < 4; i++)                        \
                _Pragma("unroll") for (int j = 0; j < 4; j++)                    \
                    acc[i][j] = __builtin_amdgcn_mfma_f32_16x16x32_bf16(         \
                        af[i], bfr[j], acc[i][j], 0, 0, 0);                      \
        }                                                                        \
    }

// ---------------- QKV GEMM (R9 + Q pre-scale) --------------------------------
__global__ __launch_bounds__(256) void k_qkv(const __bf16* __restrict__ Xb,
                                             const __bf16* __restrict__ Wt,
                                             __bf16* __restrict__ Q,
                                             __bf16* __restrict__ K,
                                             __bf16* __restrict__ Vt) {
    __shared__ __align__(16) __bf16 LDSb[2 * 128 * 64];
    __bf16* As = LDSb;
    __bf16* Bs = LDSb + 128 * 64;

    int bid  = blockIdx.x;
    int xcd  = bid & 7;
    int seq  = bid >> 3;
    int brow = (seq / 18) * 8 + xcd;
    int bcol = seq % 18;

    GEMM64_MAINLOOP(Xb, Wt, brow, bcol, T_)

    int region = bcol / 6;
    int b  = brow >> 3;
    int p0 = (brow & 7) * 128;

    if (region < 2) {
        __bf16* D = region == 0 ? Q : K;
        // Q pre-scaled by 1/8 * log2(e): attn does raw exp2(s)
        float sc = region == 0 ? 0.1803368801f : 1.0f;
#pragma unroll
        for (int j = 0; j < 4; j++) {
            int idx = (bcol - region * 6) * 128 + wn + j * 16 + l16;
            int h = idx >> 6, v = idx & 63;
            __bf16* Dh = D + ((size_t)(b * H_ + h) * P_) * DV + v;
#pragma unroll
            for (int i = 0; i < 4; i++)
#pragma unroll
                for (int r = 0; r < 4; r++)
                    Dh[(size_t)(p0 + wm + i * 16 + quad * 4 + r) * DV] =
                        (__bf16)(acc[i][j][r] * sc);
        }
    } else {
        __syncthreads();
#pragma unroll
        for (int j = 0; j < 4; j++) {
            int n_loc = wn + j * 16 + l16;
#pragma unroll
            for (int i = 0; i < 4; i++)
#pragma unroll
            for (int r = 0; r < 4; r++) {
                int m_loc = wm + i * 16 + quad * 4 + r;
                int phys  = (m_loc >> 3) ^ (n_loc & 15);
                LDSb[n_loc * 128 + phys * 8 + (m_loc & 7)] = (__bf16)acc[i][j][r];
            }
        }
        __syncthreads();
        int n_loc = tid >> 1, halfm = tid & 1;
        int idx = (bcol - 12) * 128 + n_loc;
        int h = idx >> 6, v = idx & 63;
        __bf16* Dh = Vt + ((size_t)(b * H_ + h) * DV + v) * P_ + p0 + halfm * 64;
#pragma unroll
        for (int i = 0; i < 8; i++) {
            int chunk = halfm * 8 + i;
            int phys  = chunk ^ (n_loc & 15);
            bf16x8 val = *(const bf16x8*)&LDSb[n_loc * 128 + phys * 8];
            *(bf16x8*)(Dh + i * 8) = val;
        }
    }
}

// ---------------- merge GEMM (unchanged R9) ----------------------------------
__global__ __launch_bounds__(256) void k_merge(const __bf16* __restrict__ O,
                                               const __bf16* __restrict__ Wt,
                                               float* __restrict__ out) {
    __shared__ __align__(16) __bf16 LDSb[2 * 128 * 64];
    __bf16* As = LDSb;
    __bf16* Bs = LDSb + 128 * 64;

    int bid  = blockIdx.x;
    int xcd  = bid & 7;
    int seq  = bid >> 3;
    int brow = (seq / 6) * 8 + xcd;
    int bcol = seq % 6;

    GEMM64_MAINLOOP(O, Wt, brow, bcol, HD)

#pragma unroll
    for (int i = 0; i < 4; i++)
#pragma unroll
        for (int j = 0; j < 4; j++) {
            int col = bcol * 128 + wn + j * 16 + l16;
#pragma unroll
            for (int r = 0; r < 4; r++) {
                size_t row = (size_t)(brow * 128 + wm + i * 16 + quad * 4 + r);
                out[row * HD + col] = acc[i][j][r];
            }
        }
}

// ---------------- attention R11: S^T/O^T + ones-MFMA row sums ----------------
__global__ __launch_bounds__(256) void k_attn(const __bf16* __restrict__ Q,
                                              const __bf16* __restrict__ Kb,
                                              const __bf16* __restrict__ Vt,
                                              __bf16* __restrict__ O) {
    __shared__ __align__(16) __bf16 Ks[128 * 64];
    __shared__ __align__(16) __bf16 Vs[64 * 128];
    __shared__ __align__(16) __bf16 Pb[4][16 * PSTR];

    int tid  = threadIdx.x;
    int lane = tid & 63, wave = tid >> 6;
    int l16  = lane & 15, quad = lane >> 4;

    int bid = blockIdx.x;
    int xcd = bid & 7;
    int seq = bid >> 3;
    int bh  = xcd * 12 + (seq % 12);
    int qt  = seq / 12;
    int b   = bh / H_, h = bh % H_;

    const __bf16* Qb  = Q  + (size_t)bh * P_ * DV;
    const __bf16* Kbh = Kb + (size_t)bh * P_ * DV;
    const __bf16* Vbh = Vt + (size_t)bh * DV * P_;
    int m0 = qt * 64 + wave * 16;

    bf16x8 a0 = *(const bf16x8*)(Qb + (size_t)(m0 + l16) * DV + quad * 8);
    bf16x8 a1 = *(const bf16x8*)(Qb + (size_t)(m0 + l16) * DV + 32 + quad * 8);

    int lK = lane >> 3, qK = lane & 7;
    int lV = lane >> 4, qV = lane & 15;

    bf16x8 ones;
#pragma unroll
    for (int i = 0; i < 8; i++) ones[i] = (__bf16)1.0f;

    __bf16* Pw = &Pb[wave][0];
    f32x4 facc = {0.f, 0.f, 0.f, 0.f};    // row-sum accumulator (all rows equal)
    f32x4 oacc[4] = {{0.f,0.f,0.f,0.f},{0.f,0.f,0.f,0.f},{0.f,0.f,0.f,0.f},{0.f,0.f,0.f,0.f}};
    int swq = l16 & 7;

    for (int c = 0; c < P_; c += 128) {
        __syncthreads();
#pragma unroll
        for (int i = 0; i < 4; i++) {
            int t  = wave * 4 + i;
            int rK = t * 8 + lK;
            int jK = qK ^ (rK & 7);
            gload16(Kbh + (size_t)(c + rK) * DV + jK * 8, Ks + t * 512 + lane * 8);
            int rV = t * 4 + lV;
            int jV = qV ^ (rV & 15);
            gload16(Vbh + (size_t)rV * P_ + c + jV * 8,  Vs + t * 512 + lane * 8);
        }
        __syncthreads();

        // ---- S^T = K Q^T (Q pre-scaled: s is already log2-domain) ----
        f32x4 s[8];
#pragma unroll
        for (int ct = 0; ct < 8; ct++) {
            int R = ct * 16 + l16;
            bf16x8 b0 = *(const bf16x8*)&Ks[R * 64 + ((quad ^ swq) * 8)];
            bf16x8 b1 = *(const bf16x8*)&Ks[R * 64 + (((4 + quad) ^ swq) * 8)];
            f32x4 z = {0.f, 0.f, 0.f, 0.f};
            z = __builtin_amdgcn_mfma_f32_16x16x32_bf16(b0, a0, z, 0, 0, 0);
            s[ct] = __builtin_amdgcn_mfma_f32_16x16x32_bf16(b1, a1, z, 0, 0, 0);
        }

        // ---- P^T: raw exp2, pack 4 consecutive keys, one b64 write ----
#pragma unroll
        for (int ct = 0; ct < 8; ct++) {
            bf16x4 pk;
#pragma unroll
            for (int r = 0; r < 4; r++)
                pk[r] = (__bf16)exp2f(s[ct][r]);
            *(bf16x4*)&Pw[l16 * PSTR + ct * 16 + quad * 4] = pk;
        }

        // ---- O^T += V_tile * P^T ; row sums via ones-MFMA ----
#pragma unroll
        for (int ks = 0; ks < 4; ks++) {
            bf16x8 pfrag = *(const bf16x8*)&Pw[l16 * PSTR + ks * 32 + quad * 8];
            facc = __builtin_amdgcn_mfma_f32_16x16x32_bf16(ones, pfrag, facc, 0, 0, 0);
#pragma unroll
            for (int nt = 0; nt < 4; nt++) {
                int R = nt * 16 + l16;
                bf16x8 av = *(const bf16x8*)&Vs[R * 128 + (((ks * 4 + quad) ^ l16) * 8)];
                oacc[nt] = __builtin_amdgcn_mfma_f32_16x16x32_bf16(av, pfrag, oacc[nt], 0, 0, 0);
            }
        }
    }

    // facc rows are all identical: facc[0] = sum over all 1024 keys for q=l16
    float inv = 1.0f / facc[0];

    int p = m0 + l16;
    __bf16* Orow = O + ((size_t)b * P_ + p) * HD + h * DV;
#pragma unroll
    for (int nt = 0; nt < 4; nt++) {
        bf16x4 o4;
#pragma unroll
        for (int r = 0; r < 4; r++) o4[r] = (__bf16)(oacc[nt][r] * inv);
        *(bf16x4*)&Orow[nt * 16 + quad * 4] = o4;
    }
}

extern "C" void kernel_launch(void* const* d_in, const int* in_sizes, int n_in,
                              void* d_out, int out_size, void* d_ws, size_t ws_size,
                              hipStream_t stream) {
    const float* x      = (const float*)d_in[0];
    const float* wqkv   = (const float*)d_in[1];
    const float* wmerge = (const float*)d_in[2];

    char* w = (char*)d_ws;
    __bf16* Xb  = (__bf16*)w;  w += (size_t)B_ * P_ * T_ * 2;
    __bf16* WqT = (__bf16*)w;  w += (size_t)F3 * T_ * 2;
    __bf16* WmT = (__bf16*)w;  w += (size_t)HD * T_ * 2;
    __bf16* Q   = (__bf16*)w;  w += (size_t)B_ * H_ * P_ * DV * 2;
    __bf16* K   = (__bf16*)w;  w += (size_t)B_ * H_ * P_ * DV * 2;
    __bf16* Vt  = (__bf16*)w;  w += (size_t)B_ * H_ * P_ * DV * 2;
    __bf16* O   = (__bf16*)w;

    hipLaunchKernelGGL(k_cvt, dim3(768), dim3(256), 0, stream, x, Xb);

    dim3 tb(32, 8);
    hipLaunchKernelGGL(k_tcvt_qkv, dim3(F3 / 32, T_ / 32), tb, 0, stream, wqkv, WqT);
    hipLaunchKernelGGL(k_tcvt,     dim3(HD / 32, T_ / 32), tb, 0, stream, wmerge, WmT, T_, HD);

    hipLaunchKernelGGL(k_qkv, dim3((B_ * P_ / 128) * (F3 / 128)), dim3(256), 0, stream,
                       Xb, WqT, Q, K, Vt);

    hipLaunchKernelGGL(k_attn, dim3(B_ * H_ * (P_ / 64)), dim3(256), 0, stream,
                       Q, K, Vt, O);

    hipLaunchKernelGGL(k_merge, dim3((B_ * P_ / 128) * (HD / 128)), dim3(256), 0, stream,
                       O, WmT, (float*)d_out);
}